// Round 4
// baseline (64.358 us; speedup 1.0000x reference)
//
#include <hip/hip_runtime.h>
#include <hip/hip_bf16.h>
#include <math.h>

// OHEM BCE-with-logits, shape (4,1,192,192,192) f32, scalar f32 output.
//
// R4: R3 (counts-only 4096-bin histogram of negative logits; softplus is
// monotone so top-k selects on x directly) + manual 1-deep software
// prefetch in pass1. R3's VGPR_Count=16 showed the compiler kept only one
// iteration's loads in flight -> wave memory duty-cycle ~50%. Named
// next-iteration register buffers force loads of i+1 to issue before the
// vmcnt wait on i's data.

#define NBINS 4096
#define XOFF 8.0f
#define BIN_SCALE 256.0f        // (x+8)*256 -> [0, 4096)
#define INV_BIN 0.00390625f     // 1/256

extern "C" __global__ __launch_bounds__(1024) void ohem_pass1(
    const float* __restrict__ logits, const float* __restrict__ targets,
    unsigned int* __restrict__ g_cnt,
    unsigned int* __restrict__ g_npos, float* __restrict__ g_psum,
    int n8, int n_total)
{
    __shared__ unsigned int h[NBINS];   // 16 KiB
    __shared__ unsigned int s_pcnt[16];
    __shared__ float s_psum[16];

    for (int i = threadIdx.x; i < NBINS; i += 1024) h[i] = 0u;
    __syncthreads();

    const float4* L4 = (const float4*)logits;
    const float4* T4 = (const float4*)targets;
    unsigned int pcnt = 0;
    float psum = 0.0f;
    const int stride = gridDim.x * blockDim.x;

    int i = blockIdx.x * blockDim.x + threadIdx.x;
    float4 xa, xb, ta, tb;
    xa = xb = ta = tb = make_float4(0.f, 0.f, 0.f, 0.f);
    if (i < n8) {
        xa = L4[2 * i];     xb = L4[2 * i + 1];
        ta = T4[2 * i];     tb = T4[2 * i + 1];
    }

    while (i < n8) {
        int inext = i + stride;
        float4 nxa, nxb, nta, ntb;
        nxa = nxb = nta = ntb = make_float4(0.f, 0.f, 0.f, 0.f);
        if (inext < n8) {
            // issue next iteration's loads BEFORE consuming current data
            nxa = L4[2 * inext];     nxb = L4[2 * inext + 1];
            nta = T4[2 * inext];     ntb = T4[2 * inext + 1];
        }

        float xs[8] = {xa.x, xa.y, xa.z, xa.w, xb.x, xb.y, xb.z, xb.w};
        float ts[8] = {ta.x, ta.y, ta.z, ta.w, tb.x, tb.y, tb.z, tb.w};
        #pragma unroll
        for (int j = 0; j < 8; ++j) {
            float x = xs[j];
            if (ts[j] > 0.5f) {
                // exact positive loss: softplus(-x), fast HW transcendentals
                pcnt++;
                psum += fmaxf(-x, 0.0f) + __logf(1.0f + __expf(-fabsf(x)));
            } else {
                float f = fmaxf(fmaf(x, BIN_SCALE, XOFF * BIN_SCALE), 0.0f);
                unsigned int bin = (unsigned int)f;
                bin = bin > NBINS - 1 ? NBINS - 1 : bin;
                atomicAdd(&h[bin], 1u);   // non-returning ds_add_u32
            }
        }

        xa = nxa; xb = nxb; ta = nta; tb = ntb;
        i = inext;
    }

    // tail (n_total % 8) -- not hit for this shape, kept for safety
    if (blockIdx.x == 0) {
        for (int t = n8 * 8 + threadIdx.x; t < n_total; t += 1024) {
            float x = logits[t], tv = targets[t];
            if (tv > 0.5f) {
                pcnt++;
                psum += fmaxf(-x, 0.0f) + __logf(1.0f + __expf(-fabsf(x)));
            } else {
                float f = fmaxf(fmaf(x, BIN_SCALE, XOFF * BIN_SCALE), 0.0f);
                unsigned int bin = (unsigned int)f;
                bin = bin > NBINS - 1 ? NBINS - 1 : bin;
                atomicAdd(&h[bin], 1u);
            }
        }
    }
    __syncthreads();

    // flush LDS histogram to global
    for (int b = threadIdx.x; b < NBINS; b += 1024) {
        unsigned int c = h[b];
        if (c) atomicAdd(&g_cnt[b], c);
    }

    // reduce positive count/sum: wave64 shuffle, then cross-wave via LDS
    #pragma unroll
    for (int off = 32; off > 0; off >>= 1) {
        pcnt += __shfl_down(pcnt, off);
        psum += __shfl_down(psum, off);
    }
    int wave = threadIdx.x >> 6;
    if ((threadIdx.x & 63) == 0) { s_pcnt[wave] = pcnt; s_psum[wave] = psum; }
    __syncthreads();
    if (threadIdx.x == 0) {
        unsigned int c = 0; float s = 0.0f;
        #pragma unroll
        for (int w = 0; w < 16; ++w) { c += s_pcnt[w]; s += s_psum[w]; }
        if (c) atomicAdd(g_npos, c);
        atomicAdd(g_psum, s);
    }
}

__device__ __forceinline__ float softplus_acc(float v) {
    return fmaxf(v, 0.0f) + log1pf(expf(-fabsf(v)));
}

extern "C" __global__ __launch_bounds__(256) void ohem_finalize(
    const unsigned int* __restrict__ g_cnt,
    const unsigned int* __restrict__ g_npos, const float* __restrict__ g_psum,
    float* __restrict__ out, int n_total)
{
    const int BPT = NBINS / 256; // 16 bins per thread
    __shared__ unsigned int sh_c[256];
    __shared__ float sh_s[256];
    __shared__ unsigned int suf_c[256];
    __shared__ float suf_s[256];

    int tid = threadIdx.x;
    unsigned int lc[BPT];
    float lloss[BPT];            // per-bin total loss: c * softplus(center)
    unsigned int tc = 0;
    float tsum = 0.0f;
    #pragma unroll
    for (int j = 0; j < BPT; ++j) {
        int b = tid * BPT + j;
        unsigned int c = g_cnt[b];
        lc[j] = c;
        float lb = 0.0f;
        if (c > 0) {
            float center = ((float)b + 0.5f) * INV_BIN - XOFF;
            lb = (float)c * softplus_acc(center);
        }
        lloss[j] = lb;
        tc += c;
        tsum += lb;
    }
    sh_c[tid] = tc;
    sh_s[tid] = tsum;
    __syncthreads();

    if (tid == 0) {
        // exclusive suffix totals over the 256 thread-chunks
        unsigned int rc = 0; float rs = 0.0f;
        for (int i = 255; i >= 0; --i) {
            suf_c[i] = rc; suf_s[i] = rs;
            rc += sh_c[i]; rs += sh_s[i];
        }
    }
    __syncthreads();

    unsigned int n_pos = *g_npos;
    unsigned int n_neg = (unsigned int)n_total - n_pos;
    float pos_mean = (n_pos > 0) ? (*g_psum / (float)n_pos) : 0.0f;

    if (n_neg == 0) {
        if (tid == 0) out[0] = pos_mean;
        return;
    }

    // k = max(1024, rint(0.1 * n_neg)), clamped to n_neg (RNE matches jnp.round)
    float nf = (float)n_neg;
    int k = (int)rintf(nf * 0.1f);
    if (k < 1024) k = 1024;
    if ((unsigned int)k > n_neg) k = (int)n_neg;

    // walk own chunk from the top bin down; exactly one (tid, j) crosses k
    unsigned int run_c = suf_c[tid];
    float run_s = suf_s[tid];
    #pragma unroll
    for (int j = BPT - 1; j >= 0; --j) {
        unsigned int c = lc[j];
        float lb = lloss[j];
        if (c > 0 && run_c < (unsigned int)k && run_c + c >= (unsigned int)k) {
            unsigned int m = (unsigned int)k - run_c;
            float neg_sum = run_s + (float)m * (lb / (float)c);
            float neg_mean = neg_sum / (float)k;
            out[0] = pos_mean + neg_mean;
        }
        run_c += c;
        run_s += lb;
    }
}

extern "C" void kernel_launch(void* const* d_in, const int* in_sizes, int n_in,
                              void* d_out, int out_size, void* d_ws, size_t ws_size,
                              hipStream_t stream) {
    const float* logits  = (const float*)d_in[0];
    const float* targets = (const float*)d_in[1];
    float* out = (float*)d_out;
    int n_total = in_sizes[0];
    int n8 = n_total / 8;

    unsigned int* g_cnt  = (unsigned int*)d_ws;
    unsigned int* g_npos = (unsigned int*)((char*)d_ws + NBINS * 4);
    float*        g_psum = (float*)((char*)d_ws + NBINS * 4 + 4);

    hipMemsetAsync(d_ws, 0, NBINS * 4 + 8, stream);

    // 1024-thread blocks: 512 blocks = 2 blocks/CU * 16 waves = full residency;
    // flush stays at 512 x 4096 global atomics (cheap, per R3's WRITE_SIZE).
    ohem_pass1<<<512, 1024, 0, stream>>>(logits, targets, g_cnt,
                                         g_npos, g_psum, n8, n_total);
    ohem_finalize<<<1, 256, 0, stream>>>(g_cnt, g_npos, g_psum, out, n_total);
}